// Round 13
// baseline (896.778 us; speedup 1.0000x reference)
//
#include <hip/hip_runtime.h>

#define F 64
#define TPB 256
#define SCAN_B 64
#define BN_EPS 1e-5f

typedef unsigned short u16;

__device__ __forceinline__ float lane_bcast(float v, int l) {
    return __int_as_float(__builtin_amdgcn_readlane(__float_as_int(v), l));
}
__device__ __forceinline__ int lane_bcast_i(int v, int l) {
    return __builtin_amdgcn_readlane(v, l);
}
__device__ __forceinline__ float bf2f(u16 u) {
    return __uint_as_float(((unsigned int)u) << 16);
}
__device__ __forceinline__ u16 f2bf(float f) {
    unsigned int u = __float_as_uint(f);
    unsigned int r = (u + 0x7fffu + ((u >> 16) & 1u)) >> 16;   // RNE
    return (u16)r;
}

// ---- CSR build ----------------------------------------------------------

__global__ __launch_bounds__(TPB) void k_hist(const int* __restrict__ dst,
                                              int* __restrict__ deg, int E) {
    int e = blockIdx.x * blockDim.x + threadIdx.x;
    if (e < E) atomicAdd(&deg[dst[e]], 1);
}

__global__ __launch_bounds__(TPB) void k_scan_part(const int* __restrict__ deg,
                                                   int* __restrict__ part, int N) {
    __shared__ int red[TPB];
    int chunk = (N + SCAN_B - 1) / SCAN_B;
    int lo = blockIdx.x * chunk, hi = min(lo + chunk, N);
    int t = threadIdx.x;
    int s = 0;
    for (int i = lo + t; i < hi; i += TPB) s += deg[i];
    red[t] = s; __syncthreads();
    for (int d = TPB / 2; d > 0; d >>= 1) {
        if (t < d) red[t] += red[t + d];
        __syncthreads();
    }
    if (t == 0) part[blockIdx.x] = red[0];
}

__global__ __launch_bounds__(TPB) void k_scan_apply(const int* __restrict__ deg,
                                                    const int* __restrict__ part,
                                                    int* __restrict__ offs,
                                                    int* __restrict__ cursor, int N) {
    __shared__ int ts[TPB];
    __shared__ int pb_s;
    int t = threadIdx.x;
    ts[t] = (t < blockIdx.x) ? part[t] : 0;
    __syncthreads();
    for (int d = TPB / 2; d > 0; d >>= 1) {
        if (t < d) ts[t] += ts[t + d];
        __syncthreads();
    }
    if (t == 0) pb_s = ts[0];
    __syncthreads();
    int pbase = pb_s;
    __syncthreads();
    int chunk = (N + SCAN_B - 1) / SCAN_B;
    int sub = (chunk + TPB - 1) / TPB;
    int lo = blockIdx.x * chunk;
    int blockhi = min(lo + chunk, N);
    int mylo = min(lo + t * sub, blockhi);
    int myhi = min(mylo + sub, blockhi);
    int s = 0;
    for (int i = mylo; i < myhi; ++i) s += deg[i];
    ts[t] = s; __syncthreads();
    for (int d = 1; d < TPB; d <<= 1) {
        int a = (t >= d) ? ts[t - d] : 0;
        __syncthreads();
        ts[t] += a;
        __syncthreads();
    }
    int run = pbase + ts[t] - s;
    for (int i = mylo; i < myhi; ++i) {
        offs[i] = run; cursor[i] = run; run += deg[i];
    }
    if (blockIdx.x == SCAN_B - 1 && t == TPB - 1) offs[N] = pbase + ts[TPB - 1];
}

__global__ __launch_bounds__(TPB) void k_fill(const int* __restrict__ src,
                                              const int* __restrict__ dst,
                                              int* __restrict__ cursor,
                                              int* __restrict__ csr_src, int E) {
    int e = blockIdx.x * blockDim.x + threadIdx.x;
    if (e >= E) return;
    int pos = atomicAdd(&cursor[dst[e]], 1);
    csr_src[pos] = src[e];
}

// ---- prep: x16 = bf16(x); Yf = x @ Wj + bias (fused, reads x once) ------
__global__ __launch_bounds__(TPB, 4)
void k_prep(const float* __restrict__ x, u16* __restrict__ x16,
            const float* __restrict__ Wj, const float* __restrict__ bias,
            float* __restrict__ Yf, int N, int rowsPerWave) {
    int t = threadIdx.x;
    int lane = t & 63, w = t >> 6;
    float wcol[F];
#pragma unroll
    for (int f = 0; f < F; ++f) wcol[f] = Wj[f * F + lane];
    float bj = bias[lane];
    int row0 = (blockIdx.x * 4 + w) * rowsPerWave;
    for (int r = 0; r < rowsPerWave; ++r) {
        int row = row0 + r;
        if (row >= N) break;
        float v = x[(size_t)row * F + lane];
        x16[(size_t)row * F + lane] = f2bf(v);
        float acc = bj;
#pragma unroll
        for (int f = 0; f < F; ++f) acc += lane_bcast(v, f) * wcol[f];
        Yf[(size_t)row * F + lane] = acc;
    }
}

// ---- fused gather + GEMM1 + BN stats ------------------------------------
// W in LDS (VGPR=36 measured in R12) -> LB(256,8) is spill-safe; NPW=4 gives
// 2x wave oversubscription (3125 blocks) to backfill the degree-variance tail.
__global__ __launch_bounds__(TPB, 8)
void k_gather_gemm(const u16* __restrict__ h, const int* __restrict__ offs,
                   const int* __restrict__ csr,
                   const float* __restrict__ W, const float* __restrict__ bias,
                   float* __restrict__ Y, float* __restrict__ stats,
                   int N, int nodesPerWave) {
    __shared__ float Wl[F * F];
    int t = threadIdx.x;
    int lane = t & 63, w = t >> 6;
    for (int i = t; i < F * F; i += TPB) Wl[i] = W[i];
    __syncthreads();
    float bj = bias[lane];
    int node0 = (blockIdx.x * 4 + w) * nodesPerWave;
    // offs[node0 .. node0+NPW] via lanes (clamped), broadcast later by readlane
    int off_l = 0;
    if (lane <= nodesPerWave) off_l = offs[min(node0 + lane, N)];
    float s1 = 0.f, s2 = 0.f;
    // prefetch node 0's first batch
    int start_n = lane_bcast_i(off_l, 0);
    int end_n   = lane_bcast_i(off_l, 1);
    int cnt_n   = min(end_n - start_n, 64);
    int idx_n   = (lane < cnt_n) ? csr[start_n + lane] : 0;
    for (int r = 0; r < nodesPerWave; ++r) {
        int node = node0 + r;
        if (node >= N) break;
        int start = start_n, end = end_n, cnt = cnt_n, idx = idx_n;
        // prefetch next node's first batch (clamped offs make this safe)
        if (r + 1 < nodesPerWave) {
            start_n = lane_bcast_i(off_l, r + 1);
            end_n   = lane_bcast_i(off_l, r + 2);
            cnt_n   = min(end_n - start_n, 64);
            idx_n   = (lane < cnt_n) ? csr[start_n + lane] : 0;
        }
        float agg = bf2f(h[(size_t)node * F + lane]);    // GIN self term (eps=0)
        // first batch (prefetched idx)
        {
            int k = 0;
            for (; k + 16 <= cnt; k += 16) {
                float vv[16];
#pragma unroll
                for (int u = 0; u < 16; ++u)
                    vv[u] = bf2f(h[(size_t)lane_bcast_i(idx, k + u) * F + lane]);
                float sA = 0.f, sB = 0.f, sC = 0.f, sD = 0.f;
#pragma unroll
                for (int u = 0; u < 4; ++u) {
                    sA += vv[u]; sB += vv[4 + u]; sC += vv[8 + u]; sD += vv[12 + u];
                }
                agg += (sA + sB) + (sC + sD);
            }
            for (; k + 4 <= cnt; k += 4) {
                float v0 = bf2f(h[(size_t)lane_bcast_i(idx, k)     * F + lane]);
                float v1 = bf2f(h[(size_t)lane_bcast_i(idx, k + 1) * F + lane]);
                float v2 = bf2f(h[(size_t)lane_bcast_i(idx, k + 2) * F + lane]);
                float v3 = bf2f(h[(size_t)lane_bcast_i(idx, k + 3) * F + lane]);
                agg += (v0 + v1) + (v2 + v3);
            }
            for (; k < cnt; ++k)
                agg += bf2f(h[(size_t)lane_bcast_i(idx, k) * F + lane]);
        }
        // remaining batches (degree > 64, rare)
        for (int base = start + 64; base < end; base += 64) {
            int c2 = end - base; if (c2 > 64) c2 = 64;
            int idx2 = (lane < c2) ? csr[base + lane] : 0;
            int k = 0;
            for (; k + 4 <= c2; k += 4) {
                float v0 = bf2f(h[(size_t)lane_bcast_i(idx2, k)     * F + lane]);
                float v1 = bf2f(h[(size_t)lane_bcast_i(idx2, k + 1) * F + lane]);
                float v2 = bf2f(h[(size_t)lane_bcast_i(idx2, k + 2) * F + lane]);
                float v3 = bf2f(h[(size_t)lane_bcast_i(idx2, k + 3) * F + lane]);
                agg += (v0 + v1) + (v2 + v3);
            }
            for (; k < c2; ++k)
                agg += bf2f(h[(size_t)lane_bcast_i(idx2, k) * F + lane]);
        }
        // GEMM from LDS W (stride-64 f32 = 2-way bank aliasing = free)
        float acc = bj;
#pragma unroll
        for (int f = 0; f < F; ++f) acc += lane_bcast(agg, f) * Wl[f * F + lane];
        Y[(size_t)node * F + lane] = acc;
        s1 += acc;
        s2 += acc * acc;
    }
    __shared__ float red[TPB];
    red[t] = s1; __syncthreads();
    if (w == 0) atomicAdd(&stats[lane], red[lane] + red[64 + lane] + red[128 + lane] + red[192 + lane]);
    __syncthreads();
    red[t] = s2; __syncthreads();
    if (w == 0) atomicAdd(&stats[64 + lane], red[lane] + red[64 + lane] + red[128 + lane] + red[192 + lane]);
}

// ---- fused: BN(Y)+ReLU -> GEMM2 -> ReLU -> Hout(bf16); Yf += Hout @ Wj --
__global__ __launch_bounds__(TPB, 3)
void k_layerB(const float* __restrict__ Y, const float* __restrict__ stats,
              const float* __restrict__ g, const float* __restrict__ bt,
              const float* __restrict__ W2, const float* __restrict__ b2,
              const float* __restrict__ Wj,
              u16* __restrict__ Hout, float* __restrict__ Yf,
              float* __restrict__ stats5, int N, int rowsPerWave, int doHead) {
    int t = threadIdx.x;
    int lane = t & 63, w = t >> 6;
    float wc2[F], wcj[F];
#pragma unroll
    for (int f = 0; f < F; ++f) { wc2[f] = W2[f * F + lane]; wcj[f] = Wj[f * F + lane]; }
    float mu = stats[lane] / (float)N;
    float var = stats[64 + lane] / (float)N - mu * mu;
    float rs = rsqrtf(var + BN_EPS);
    float sc = rs * g[lane];
    float sh = bt[lane] - mu * sc;
    float bj = b2[lane];
    int row0 = (blockIdx.x * 4 + w) * rowsPerWave;
    float s1 = 0.f, s2 = 0.f;
    for (int r = 0; r < rowsPerWave; ++r) {
        int row = row0 + r;
        if (row >= N) break;
        float v = fmaxf(Y[(size_t)row * F + lane] * sc + sh, 0.f);
        float acc = bj;
#pragma unroll
        for (int f = 0; f < F; ++f) acc += lane_bcast(v, f) * wc2[f];
        float hv = fmaxf(acc, 0.f);
        Hout[(size_t)row * F + lane] = f2bf(hv);
        float yf = Yf[(size_t)row * F + lane];
#pragma unroll
        for (int f = 0; f < F; ++f) yf += lane_bcast(hv, f) * wcj[f];
        Yf[(size_t)row * F + lane] = yf;
        if (doHead) { s1 += yf; s2 += yf * yf; }
    }
    if (doHead) {
        __shared__ float red[TPB];
        red[t] = s1; __syncthreads();
        if (w == 0) atomicAdd(&stats5[lane], red[lane] + red[64 + lane] + red[128 + lane] + red[192 + lane]);
        __syncthreads();
        red[t] = s2; __syncthreads();
        if (w == 0) atomicAdd(&stats5[64 + lane], red[lane] + red[64 + lane] + red[128 + lane] + red[192 + lane]);
    }
}

// ---- head: BN(Yf)+ReLU -> @mlpW2+b2 -> pooled add into out[graph] -------
__global__ __launch_bounds__(TPB, 4)
void k_final(const float* __restrict__ Yf, const float* __restrict__ stats,
             const float* __restrict__ g, const float* __restrict__ bt,
             const float* __restrict__ W2, const float* __restrict__ b2,
             const int* __restrict__ batch, float* __restrict__ out,
             int N, int rowsPerWave) {
    int t = threadIdx.x;
    int lane = t & 63, w = t >> 6;
    float wcol[F];
#pragma unroll
    for (int f = 0; f < F; ++f) wcol[f] = W2[f * F + lane];
    float mu = stats[lane] / (float)N;
    float var = stats[64 + lane] / (float)N - mu * mu;
    float rs = rsqrtf(var + BN_EPS);
    float sc = rs * g[lane];
    float sh = bt[lane] - mu * sc;
    float bj = b2[lane];
    int row0 = (blockIdx.x * 4 + w) * rowsPerWave;
    int curg = -1;
    float accg = 0.f;
    for (int r = 0; r < rowsPerWave; ++r) {
        int row = row0 + r;
        if (row >= N) break;
        float v = fmaxf(Yf[(size_t)row * F + lane] * sc + sh, 0.f);
        float acc = bj;
#pragma unroll
        for (int f = 0; f < F; ++f) acc += lane_bcast(v, f) * wcol[f];
        int gid = batch[row];
        if (gid != curg) {
            if (curg >= 0) atomicAdd(&out[(size_t)curg * F + lane], accg);
            curg = gid;
            accg = 0.f;
        }
        accg += acc;
    }
    if (curg >= 0) atomicAdd(&out[(size_t)curg * F + lane], accg);
}

// ---- launcher -----------------------------------------------------------

extern "C" void kernel_launch(void* const* d_in, const int* in_sizes, int n_in,
                              void* d_out, int out_size, void* d_ws, size_t ws_size,
                              hipStream_t stream) {
    const float* x      = (const float*)d_in[0];
    const int*   ei     = (const int*)d_in[1];
    const int*   batch  = (const int*)d_in[2];
    const float* convW1 = (const float*)d_in[3];
    const float* convb1 = (const float*)d_in[4];
    const float* convg  = (const float*)d_in[5];
    const float* convbt = (const float*)d_in[6];
    const float* convW2 = (const float*)d_in[7];
    const float* convb2 = (const float*)d_in[8];
    const float* mlpW1  = (const float*)d_in[9];
    const float* mlpb1  = (const float*)d_in[10];
    const float* mlpg   = (const float*)d_in[11];
    const float* mlpbt  = (const float*)d_in[12];
    const float* mlpW2  = (const float*)d_in[13];
    const float* mlpb2  = (const float*)d_in[14];

    const int N = in_sizes[0] / F;             // 50000
    const int E = in_sizes[1] / 2;             // 800000
    const int L = in_sizes[3] / (F * F);       // 5

    const int* src = ei;
    const int* dst = ei + E;

    char* w = (char*)d_ws;
    size_t off = 0;
    auto alloc = [&](size_t bytes) {
        void* p = w + off;
        off = (off + bytes + 255) & ~(size_t)255;
        return p;
    };
    u16*   x16     = (u16*)alloc((size_t)N * F * 2);
    u16*   hA16    = (u16*)alloc((size_t)N * F * 2);
    u16*   hB16    = (u16*)alloc((size_t)N * F * 2);
    float* Ytmp    = (float*)alloc((size_t)N * F * 4);
    float* Yf      = (float*)alloc((size_t)N * F * 4);
    int*   deg     = (int*)alloc((size_t)N * 4);
    int*   offs    = (int*)alloc((size_t)(N + 1) * 4);
    int*   cursor  = (int*)alloc((size_t)N * 4);
    int*   csr_src = (int*)alloc((size_t)E * 4);
    int*   part    = (int*)alloc((size_t)SCAN_B * 4);
    float* stats   = (float*)alloc((size_t)(L + 1) * 128 * 4);

    hipMemsetAsync(deg, 0, (size_t)N * 4, stream);
    hipMemsetAsync(stats, 0, (size_t)(L + 1) * 128 * 4, stream);
    hipMemsetAsync(d_out, 0, (size_t)out_size * 4, stream);

    const int edgeBlocks = (E + TPB - 1) / TPB;

    k_hist<<<edgeBlocks, TPB, 0, stream>>>(dst, deg, E);
    k_scan_part<<<SCAN_B, TPB, 0, stream>>>(deg, part, N);
    k_scan_apply<<<SCAN_B, TPB, 0, stream>>>(deg, part, offs, cursor, N);
    k_fill<<<edgeBlocks, TPB, 0, stream>>>(src, dst, cursor, csr_src, E);

    const int NPW_A = 4;     // 3125 blocks -> 12.2 waves/SIMD requested, 8 resident
    const int RPW   = 8;
    const int RPW_F = 16;
    const int blocksA = (N + 4 * NPW_A - 1) / (4 * NPW_A);
    const int blocksD = (N + 4 * RPW - 1) / (4 * RPW);
    const int blocksF = (N + 4 * RPW_F - 1) / (4 * RPW_F);

    // fused bf16-convert + JK-init (reads x once)
    k_prep<<<blocksD, TPB, 0, stream>>>(x, x16, mlpW1, mlpb1, Yf, N, RPW);

    const u16* h_cur = x16;
    for (int l = 0; l < L; ++l) {
        u16* h_next = (l & 1) ? hB16 : hA16;
        k_gather_gemm<<<blocksA, TPB, 0, stream>>>(h_cur, offs, csr_src,
                                                   convW1 + l * F * F, convb1 + l * F,
                                                   Ytmp, stats + l * 128, N, NPW_A);
        k_layerB<<<blocksD, TPB, 0, stream>>>(Ytmp, stats + l * 128,
                                              convg + l * F, convbt + l * F,
                                              convW2 + l * F * F, convb2 + l * F,
                                              mlpW1 + (l + 1) * F * F,
                                              h_next, Yf, stats + L * 128,
                                              N, RPW, l == L - 1);
        h_cur = h_next;
    }

    k_final<<<blocksF, TPB, 0, stream>>>(Yf, stats + L * 128, mlpg, mlpbt,
                                         mlpW2, mlpb2, batch, (float*)d_out, N, RPW_F);
}

// Round 14
// 773.895 us; speedup vs baseline: 1.1588x; 1.1588x over previous
//
#include <hip/hip_runtime.h>

#define F 64
#define TPB 256
#define SCAN_B 64
#define BN_EPS 1e-5f

typedef unsigned short u16;

__device__ __forceinline__ float lane_bcast(float v, int l) {
    return __int_as_float(__builtin_amdgcn_readlane(__float_as_int(v), l));
}
__device__ __forceinline__ int lane_bcast_i(int v, int l) {
    return __builtin_amdgcn_readlane(v, l);
}
__device__ __forceinline__ float bf2f(u16 u) {
    return __uint_as_float(((unsigned int)u) << 16);
}
__device__ __forceinline__ u16 f2bf(float f) {
    unsigned int u = __float_as_uint(f);
    unsigned int r = (u + 0x7fffu + ((u >> 16) & 1u)) >> 16;   // RNE
    return (u16)r;
}

// ---- CSR build ----------------------------------------------------------

__global__ __launch_bounds__(TPB) void k_hist(const int* __restrict__ dst,
                                              int* __restrict__ deg, int E) {
    int e = blockIdx.x * blockDim.x + threadIdx.x;
    if (e < E) atomicAdd(&deg[dst[e]], 1);
}

__global__ __launch_bounds__(TPB) void k_scan_part(const int* __restrict__ deg,
                                                   int* __restrict__ part, int N) {
    __shared__ int red[TPB];
    int chunk = (N + SCAN_B - 1) / SCAN_B;
    int lo = blockIdx.x * chunk, hi = min(lo + chunk, N);
    int t = threadIdx.x;
    int s = 0;
    for (int i = lo + t; i < hi; i += TPB) s += deg[i];
    red[t] = s; __syncthreads();
    for (int d = TPB / 2; d > 0; d >>= 1) {
        if (t < d) red[t] += red[t + d];
        __syncthreads();
    }
    if (t == 0) part[blockIdx.x] = red[0];
}

__global__ __launch_bounds__(TPB) void k_scan_apply(const int* __restrict__ deg,
                                                    const int* __restrict__ part,
                                                    int* __restrict__ offs,
                                                    int* __restrict__ cursor, int N) {
    __shared__ int ts[TPB];
    __shared__ int pb_s;
    int t = threadIdx.x;
    ts[t] = (t < blockIdx.x) ? part[t] : 0;
    __syncthreads();
    for (int d = TPB / 2; d > 0; d >>= 1) {
        if (t < d) ts[t] += ts[t + d];
        __syncthreads();
    }
    if (t == 0) pb_s = ts[0];
    __syncthreads();
    int pbase = pb_s;
    __syncthreads();
    int chunk = (N + SCAN_B - 1) / SCAN_B;
    int sub = (chunk + TPB - 1) / TPB;
    int lo = blockIdx.x * chunk;
    int blockhi = min(lo + chunk, N);
    int mylo = min(lo + t * sub, blockhi);
    int myhi = min(mylo + sub, blockhi);
    int s = 0;
    for (int i = mylo; i < myhi; ++i) s += deg[i];
    ts[t] = s; __syncthreads();
    for (int d = 1; d < TPB; d <<= 1) {
        int a = (t >= d) ? ts[t - d] : 0;
        __syncthreads();
        ts[t] += a;
        __syncthreads();
    }
    int run = pbase + ts[t] - s;
    for (int i = mylo; i < myhi; ++i) {
        offs[i] = run; cursor[i] = run; run += deg[i];
    }
    if (blockIdx.x == SCAN_B - 1 && t == TPB - 1) offs[N] = pbase + ts[TPB - 1];
}

__global__ __launch_bounds__(TPB) void k_fill(const int* __restrict__ src,
                                              const int* __restrict__ dst,
                                              int* __restrict__ cursor,
                                              int* __restrict__ csr_src, int E) {
    int e = blockIdx.x * blockDim.x + threadIdx.x;
    if (e >= E) return;
    int pos = atomicAdd(&cursor[dst[e]], 1);
    csr_src[pos] = src[e];
}

// ---- prep: x16 = bf16(x); Yf = x @ Wj + bias (fused, reads x once) ------
__global__ __launch_bounds__(TPB, 4)
void k_prep(const float* __restrict__ x, u16* __restrict__ x16,
            const float* __restrict__ Wj, const float* __restrict__ bias,
            float* __restrict__ Yf, int N, int rowsPerWave) {
    int t = threadIdx.x;
    int lane = t & 63, w = t >> 6;
    float wcol[F];
#pragma unroll
    for (int f = 0; f < F; ++f) wcol[f] = Wj[f * F + lane];
    float bj = bias[lane];
    int row0 = (blockIdx.x * 4 + w) * rowsPerWave;
    for (int r = 0; r < rowsPerWave; ++r) {
        int row = row0 + r;
        if (row >= N) break;
        float v = x[(size_t)row * F + lane];
        x16[(size_t)row * F + lane] = f2bf(v);
        float acc = bj;
#pragma unroll
        for (int f = 0; f < F; ++f) acc += lane_bcast(v, f) * wcol[f];
        Yf[(size_t)row * F + lane] = acc;
    }
}

// ---- fused gather + GEMM1 + BN stats ------------------------------------
// Packed gather: lane = (sub=lane>>4 neighbor slot, fg=lane&15 feature group).
// Index select via readlane (SALU) + cndmask (VALU) -- NOT ds_bpermute (R8 trap).
// One uint2 load = 4 bf16 features; 4 rows per instruction; slot-reduce via
// 2 shfl_xor per node (off the load chain). R12 config: LB(256,4), NPW=8.
__global__ __launch_bounds__(TPB, 4)
void k_gather_gemm(const u16* __restrict__ h, const int* __restrict__ offs,
                   const int* __restrict__ csr,
                   const float* __restrict__ W, const float* __restrict__ bias,
                   float* __restrict__ Y, float* __restrict__ stats,
                   int N, int nodesPerWave) {
    __shared__ float Wl[F * F];
    int t = threadIdx.x;
    int lane = t & 63, w = t >> 6;
    for (int i = t; i < F * F; i += TPB) Wl[i] = W[i];
    __syncthreads();
    int sub = lane >> 4;          // neighbor slot 0..3
    int fg  = lane & 15;          // feature group (4 bf16)
    int s_and1 = sub & 1, s_and2 = sub & 2;
    float bj = bias[lane];
    int node0 = (blockIdx.x * 4 + w) * nodesPerWave;
    int off_l = 0;
    if (lane <= nodesPerWave) off_l = offs[min(node0 + lane, N)];
    float s1 = 0.f, s2 = 0.f;
    int start_n = lane_bcast_i(off_l, 0);
    int end_n   = lane_bcast_i(off_l, 1);
    int cnt_n   = min(end_n - start_n, 64);
    int idx_n   = (lane < cnt_n) ? csr[start_n + lane] : 0;
    for (int r = 0; r < nodesPerWave; ++r) {
        int node = node0 + r;
        if (node >= N) break;
        int start = start_n, end = end_n, cnt = cnt_n, idx = idx_n;
        if (r + 1 < nodesPerWave) {
            start_n = lane_bcast_i(off_l, r + 1);
            end_n   = lane_bcast_i(off_l, r + 2);
            cnt_n   = min(end_n - start_n, 64);
            idx_n   = (lane < cnt_n) ? csr[start_n + lane] : 0;
        }
        float sx = 0.f, sy = 0.f, sz = 0.f, sw = 0.f;
        // packed gather over first batch (prefetched idx)
        {
            int k = 0;
            for (; k + 16 <= cnt; k += 16) {             // 4 packed loads in flight
                uint2 vv[4];
#pragma unroll
                for (int u = 0; u < 4; ++u) {
                    int kk = k + 4 * u;
                    int n0 = lane_bcast_i(idx, kk),     n1 = lane_bcast_i(idx, kk + 1);
                    int n2 = lane_bcast_i(idx, kk + 2), n3 = lane_bcast_i(idx, kk + 3);
                    int a  = s_and1 ? n1 : n0;
                    int b  = s_and1 ? n3 : n2;
                    int ns = s_and2 ? b : a;
                    vv[u] = *(const uint2*)(h + (size_t)ns * F + fg * 4);
                }
#pragma unroll
                for (int u = 0; u < 4; ++u) {
                    sx += __uint_as_float(vv[u].x << 16);
                    sy += __uint_as_float(vv[u].x & 0xffff0000u);
                    sz += __uint_as_float(vv[u].y << 16);
                    sw += __uint_as_float(vv[u].y & 0xffff0000u);
                }
            }
            for (; k < cnt; k += 4) {                    // masked tail
                int n0 = lane_bcast_i(idx, k),     n1 = lane_bcast_i(idx, k + 1);
                int n2 = lane_bcast_i(idx, k + 2), n3 = lane_bcast_i(idx, k + 3);
                int a  = s_and1 ? n1 : n0;
                int b  = s_and1 ? n3 : n2;
                int ns = s_and2 ? b : a;
                uint2 vv = *(const uint2*)(h + (size_t)ns * F + fg * 4);
                bool ok = (k + sub < cnt);
                sx += ok ? __uint_as_float(vv.x << 16) : 0.f;
                sy += ok ? __uint_as_float(vv.x & 0xffff0000u) : 0.f;
                sz += ok ? __uint_as_float(vv.y << 16) : 0.f;
                sw += ok ? __uint_as_float(vv.y & 0xffff0000u) : 0.f;
            }
        }
        // remaining batches (degree > 64, rare)
        for (int base = start + 64; base < end; base += 64) {
            int c2 = end - base; if (c2 > 64) c2 = 64;
            int idx2 = (lane < c2) ? csr[base + lane] : 0;
            for (int k = 0; k < c2; k += 4) {
                int n0 = lane_bcast_i(idx2, k),     n1 = lane_bcast_i(idx2, k + 1);
                int n2 = lane_bcast_i(idx2, k + 2), n3 = lane_bcast_i(idx2, k + 3);
                int a  = s_and1 ? n1 : n0;
                int b  = s_and1 ? n3 : n2;
                int ns = s_and2 ? b : a;
                uint2 vv = *(const uint2*)(h + (size_t)ns * F + fg * 4);
                bool ok = (k + sub < c2);
                sx += ok ? __uint_as_float(vv.x << 16) : 0.f;
                sy += ok ? __uint_as_float(vv.x & 0xffff0000u) : 0.f;
                sz += ok ? __uint_as_float(vv.y << 16) : 0.f;
                sw += ok ? __uint_as_float(vv.y & 0xffff0000u) : 0.f;
            }
        }
        // reduce the 4 neighbor slots (lanes L, L^16, L^32, L^48)
        sx += __shfl_xor(sx, 32, 64); sy += __shfl_xor(sy, 32, 64);
        sz += __shfl_xor(sz, 32, 64); sw += __shfl_xor(sw, 32, 64);
        sx += __shfl_xor(sx, 16, 64); sy += __shfl_xor(sy, 16, 64);
        sz += __shfl_xor(sz, 16, 64); sw += __shfl_xor(sw, 16, 64);
        // GIN self term (eps=0), added once after slot reduce
        uint2 sv = *(const uint2*)(h + (size_t)node * F + fg * 4);
        sx += __uint_as_float(sv.x << 16);
        sy += __uint_as_float(sv.x & 0xffff0000u);
        sz += __uint_as_float(sv.y << 16);
        sw += __uint_as_float(sv.y & 0xffff0000u);
        // GEMM from LDS W: lane g holds features 4g..4g+3 in (sx,sy,sz,sw)
        float acc = bj;
#pragma unroll
        for (int g = 0; g < 16; ++g) {
            acc += lane_bcast(sx, g) * Wl[(4 * g)     * F + lane];
            acc += lane_bcast(sy, g) * Wl[(4 * g + 1) * F + lane];
            acc += lane_bcast(sz, g) * Wl[(4 * g + 2) * F + lane];
            acc += lane_bcast(sw, g) * Wl[(4 * g + 3) * F + lane];
        }
        Y[(size_t)node * F + lane] = acc;
        s1 += acc;
        s2 += acc * acc;
    }
    __shared__ float red[TPB];
    red[t] = s1; __syncthreads();
    if (w == 0) atomicAdd(&stats[lane], red[lane] + red[64 + lane] + red[128 + lane] + red[192 + lane]);
    __syncthreads();
    red[t] = s2; __syncthreads();
    if (w == 0) atomicAdd(&stats[64 + lane], red[lane] + red[64 + lane] + red[128 + lane] + red[192 + lane]);
}

// ---- fused: BN(Y)+ReLU -> GEMM2 -> ReLU -> Hout(bf16); Yf += Hout @ Wj --
__global__ __launch_bounds__(TPB, 3)
void k_layerB(const float* __restrict__ Y, const float* __restrict__ stats,
              const float* __restrict__ g, const float* __restrict__ bt,
              const float* __restrict__ W2, const float* __restrict__ b2,
              const float* __restrict__ Wj,
              u16* __restrict__ Hout, float* __restrict__ Yf,
              float* __restrict__ stats5, int N, int rowsPerWave, int doHead) {
    int t = threadIdx.x;
    int lane = t & 63, w = t >> 6;
    float wc2[F], wcj[F];
#pragma unroll
    for (int f = 0; f < F; ++f) { wc2[f] = W2[f * F + lane]; wcj[f] = Wj[f * F + lane]; }
    float mu = stats[lane] / (float)N;
    float var = stats[64 + lane] / (float)N - mu * mu;
    float rs = rsqrtf(var + BN_EPS);
    float sc = rs * g[lane];
    float sh = bt[lane] - mu * sc;
    float bj = b2[lane];
    int row0 = (blockIdx.x * 4 + w) * rowsPerWave;
    float s1 = 0.f, s2 = 0.f;
    for (int r = 0; r < rowsPerWave; ++r) {
        int row = row0 + r;
        if (row >= N) break;
        float v = fmaxf(Y[(size_t)row * F + lane] * sc + sh, 0.f);
        float acc = bj;
#pragma unroll
        for (int f = 0; f < F; ++f) acc += lane_bcast(v, f) * wc2[f];
        float hv = fmaxf(acc, 0.f);
        Hout[(size_t)row * F + lane] = f2bf(hv);
        float yf = Yf[(size_t)row * F + lane];
#pragma unroll
        for (int f = 0; f < F; ++f) yf += lane_bcast(hv, f) * wcj[f];
        Yf[(size_t)row * F + lane] = yf;
        if (doHead) { s1 += yf; s2 += yf * yf; }
    }
    if (doHead) {
        __shared__ float red[TPB];
        red[t] = s1; __syncthreads();
        if (w == 0) atomicAdd(&stats5[lane], red[lane] + red[64 + lane] + red[128 + lane] + red[192 + lane]);
        __syncthreads();
        red[t] = s2; __syncthreads();
        if (w == 0) atomicAdd(&stats5[64 + lane], red[lane] + red[64 + lane] + red[128 + lane] + red[192 + lane]);
    }
}

// ---- head: BN(Yf)+ReLU -> @mlpW2+b2 -> pooled add into out[graph] -------
__global__ __launch_bounds__(TPB, 4)
void k_final(const float* __restrict__ Yf, const float* __restrict__ stats,
             const float* __restrict__ g, const float* __restrict__ bt,
             const float* __restrict__ W2, const float* __restrict__ b2,
             const int* __restrict__ batch, float* __restrict__ out,
             int N, int rowsPerWave) {
    int t = threadIdx.x;
    int lane = t & 63, w = t >> 6;
    float wcol[F];
#pragma unroll
    for (int f = 0; f < F; ++f) wcol[f] = W2[f * F + lane];
    float mu = stats[lane] / (float)N;
    float var = stats[64 + lane] / (float)N - mu * mu;
    float rs = rsqrtf(var + BN_EPS);
    float sc = rs * g[lane];
    float sh = bt[lane] - mu * sc;
    float bj = b2[lane];
    int row0 = (blockIdx.x * 4 + w) * rowsPerWave;
    int curg = -1;
    float accg = 0.f;
    for (int r = 0; r < rowsPerWave; ++r) {
        int row = row0 + r;
        if (row >= N) break;
        float v = fmaxf(Yf[(size_t)row * F + lane] * sc + sh, 0.f);
        float acc = bj;
#pragma unroll
        for (int f = 0; f < F; ++f) acc += lane_bcast(v, f) * wcol[f];
        int gid = batch[row];
        if (gid != curg) {
            if (curg >= 0) atomicAdd(&out[(size_t)curg * F + lane], accg);
            curg = gid;
            accg = 0.f;
        }
        accg += acc;
    }
    if (curg >= 0) atomicAdd(&out[(size_t)curg * F + lane], accg);
}

// ---- launcher -----------------------------------------------------------

extern "C" void kernel_launch(void* const* d_in, const int* in_sizes, int n_in,
                              void* d_out, int out_size, void* d_ws, size_t ws_size,
                              hipStream_t stream) {
    const float* x      = (const float*)d_in[0];
    const int*   ei     = (const int*)d_in[1];
    const int*   batch  = (const int*)d_in[2];
    const float* convW1 = (const float*)d_in[3];
    const float* convb1 = (const float*)d_in[4];
    const float* convg  = (const float*)d_in[5];
    const float* convbt = (const float*)d_in[6];
    const float* convW2 = (const float*)d_in[7];
    const float* convb2 = (const float*)d_in[8];
    const float* mlpW1  = (const float*)d_in[9];
    const float* mlpb1  = (const float*)d_in[10];
    const float* mlpg   = (const float*)d_in[11];
    const float* mlpbt  = (const float*)d_in[12];
    const float* mlpW2  = (const float*)d_in[13];
    const float* mlpb2  = (const float*)d_in[14];

    const int N = in_sizes[0] / F;             // 50000
    const int E = in_sizes[1] / 2;             // 800000
    const int L = in_sizes[3] / (F * F);       // 5

    const int* src = ei;
    const int* dst = ei + E;

    char* w = (char*)d_ws;
    size_t off = 0;
    auto alloc = [&](size_t bytes) {
        void* p = w + off;
        off = (off + bytes + 255) & ~(size_t)255;
        return p;
    };
    u16*   x16     = (u16*)alloc((size_t)N * F * 2);
    u16*   hA16    = (u16*)alloc((size_t)N * F * 2);
    u16*   hB16    = (u16*)alloc((size_t)N * F * 2);
    float* Ytmp    = (float*)alloc((size_t)N * F * 4);
    float* Yf      = (float*)alloc((size_t)N * F * 4);
    int*   deg     = (int*)alloc((size_t)N * 4);
    int*   offs    = (int*)alloc((size_t)(N + 1) * 4);
    int*   cursor  = (int*)alloc((size_t)N * 4);
    int*   csr_src = (int*)alloc((size_t)E * 4);
    int*   part    = (int*)alloc((size_t)SCAN_B * 4);
    float* stats   = (float*)alloc((size_t)(L + 1) * 128 * 4);

    hipMemsetAsync(deg, 0, (size_t)N * 4, stream);
    hipMemsetAsync(stats, 0, (size_t)(L + 1) * 128 * 4, stream);
    hipMemsetAsync(d_out, 0, (size_t)out_size * 4, stream);

    const int edgeBlocks = (E + TPB - 1) / TPB;

    k_hist<<<edgeBlocks, TPB, 0, stream>>>(dst, deg, E);
    k_scan_part<<<SCAN_B, TPB, 0, stream>>>(deg, part, N);
    k_scan_apply<<<SCAN_B, TPB, 0, stream>>>(deg, part, offs, cursor, N);
    k_fill<<<edgeBlocks, TPB, 0, stream>>>(src, dst, cursor, csr_src, E);

    const int NPW_A = 8;     // R12 proven config
    const int RPW   = 8;
    const int RPW_F = 16;
    const int blocksA = (N + 4 * NPW_A - 1) / (4 * NPW_A);
    const int blocksD = (N + 4 * RPW - 1) / (4 * RPW);
    const int blocksF = (N + 4 * RPW_F - 1) / (4 * RPW_F);

    // fused bf16-convert + JK-init (reads x once)
    k_prep<<<blocksD, TPB, 0, stream>>>(x, x16, mlpW1, mlpb1, Yf, N, RPW);

    const u16* h_cur = x16;
    for (int l = 0; l < L; ++l) {
        u16* h_next = (l & 1) ? hB16 : hA16;
        k_gather_gemm<<<blocksA, TPB, 0, stream>>>(h_cur, offs, csr_src,
                                                   convW1 + l * F * F, convb1 + l * F,
                                                   Ytmp, stats + l * 128, N, NPW_A);
        k_layerB<<<blocksD, TPB, 0, stream>>>(Ytmp, stats + l * 128,
                                              convg + l * F, convbt + l * F,
                                              convW2 + l * F * F, convb2 + l * F,
                                              mlpW1 + (l + 1) * F * F,
                                              h_next, Yf, stats + L * 128,
                                              N, RPW, l == L - 1);
        h_cur = h_next;
    }

    k_final<<<blocksF, TPB, 0, stream>>>(Yf, stats + L * 128, mlpg, mlpbt,
                                         mlpW2, mlpb2, batch, (float*)d_out, N, RPW_F);
}

// Round 15
// 743.880 us; speedup vs baseline: 1.2055x; 1.0403x over previous
//
#include <hip/hip_runtime.h>

#define F 64
#define TPB 256
#define SCAN_B 64
#define BN_EPS 1e-5f

typedef unsigned short u16;

__device__ __forceinline__ float lane_bcast(float v, int l) {
    return __int_as_float(__builtin_amdgcn_readlane(__float_as_int(v), l));
}
__device__ __forceinline__ int lane_bcast_i(int v, int l) {
    return __builtin_amdgcn_readlane(v, l);
}
__device__ __forceinline__ float bf2f(u16 u) {
    return __uint_as_float(((unsigned int)u) << 16);
}
__device__ __forceinline__ u16 f2bf(float f) {
    unsigned int u = __float_as_uint(f);
    unsigned int r = (u + 0x7fffu + ((u >> 16) & 1u)) >> 16;   // RNE
    return (u16)r;
}

// ---- CSR build ----------------------------------------------------------

__global__ __launch_bounds__(TPB) void k_hist(const int* __restrict__ dst,
                                              int* __restrict__ deg, int E) {
    int e = blockIdx.x * blockDim.x + threadIdx.x;
    if (e < E) atomicAdd(&deg[dst[e]], 1);
}

__global__ __launch_bounds__(TPB) void k_scan_part(const int* __restrict__ deg,
                                                   int* __restrict__ part, int N) {
    __shared__ int red[TPB];
    int chunk = (N + SCAN_B - 1) / SCAN_B;
    int lo = blockIdx.x * chunk, hi = min(lo + chunk, N);
    int t = threadIdx.x;
    int s = 0;
    for (int i = lo + t; i < hi; i += TPB) s += deg[i];
    red[t] = s; __syncthreads();
    for (int d = TPB / 2; d > 0; d >>= 1) {
        if (t < d) red[t] += red[t + d];
        __syncthreads();
    }
    if (t == 0) part[blockIdx.x] = red[0];
}

__global__ __launch_bounds__(TPB) void k_scan_apply(const int* __restrict__ deg,
                                                    const int* __restrict__ part,
                                                    int* __restrict__ offs,
                                                    int* __restrict__ cursor, int N) {
    __shared__ int ts[TPB];
    __shared__ int pb_s;
    int t = threadIdx.x;
    ts[t] = (t < blockIdx.x) ? part[t] : 0;
    __syncthreads();
    for (int d = TPB / 2; d > 0; d >>= 1) {
        if (t < d) ts[t] += ts[t + d];
        __syncthreads();
    }
    if (t == 0) pb_s = ts[0];
    __syncthreads();
    int pbase = pb_s;
    __syncthreads();
    int chunk = (N + SCAN_B - 1) / SCAN_B;
    int sub = (chunk + TPB - 1) / TPB;
    int lo = blockIdx.x * chunk;
    int blockhi = min(lo + chunk, N);
    int mylo = min(lo + t * sub, blockhi);
    int myhi = min(mylo + sub, blockhi);
    int s = 0;
    for (int i = mylo; i < myhi; ++i) s += deg[i];
    ts[t] = s; __syncthreads();
    for (int d = 1; d < TPB; d <<= 1) {
        int a = (t >= d) ? ts[t - d] : 0;
        __syncthreads();
        ts[t] += a;
        __syncthreads();
    }
    int run = pbase + ts[t] - s;
    for (int i = mylo; i < myhi; ++i) {
        offs[i] = run; cursor[i] = run; run += deg[i];
    }
    if (blockIdx.x == SCAN_B - 1 && t == TPB - 1) offs[N] = pbase + ts[TPB - 1];
}

__global__ __launch_bounds__(TPB) void k_fill(const int* __restrict__ src,
                                              const int* __restrict__ dst,
                                              int* __restrict__ cursor,
                                              int* __restrict__ csr_src, int E) {
    int e = blockIdx.x * blockDim.x + threadIdx.x;
    if (e >= E) return;
    int pos = atomicAdd(&cursor[dst[e]], 1);
    csr_src[pos] = src[e];
}

// ---- prep: x16 = bf16(x); Yf = x @ Wj + bias (fused, reads x once) ------
__global__ __launch_bounds__(TPB, 4)
void k_prep(const float* __restrict__ x, u16* __restrict__ x16,
            const float* __restrict__ Wj, const float* __restrict__ bias,
            float* __restrict__ Yf, int N, int rowsPerWave) {
    int t = threadIdx.x;
    int lane = t & 63, w = t >> 6;
    float wcol[F];
#pragma unroll
    for (int f = 0; f < F; ++f) wcol[f] = Wj[f * F + lane];
    float bj = bias[lane];
    int row0 = (blockIdx.x * 4 + w) * rowsPerWave;
    for (int r = 0; r < rowsPerWave; ++r) {
        int row = row0 + r;
        if (row >= N) break;
        float v = x[(size_t)row * F + lane];
        x16[(size_t)row * F + lane] = f2bf(v);
        float acc = bj;
#pragma unroll
        for (int f = 0; f < F; ++f) acc += lane_bcast(v, f) * wcol[f];
        Yf[(size_t)row * F + lane] = acc;
    }
}

// ---- fused gather + GEMM1 + BN stats ------------------------------------
// R12 structure (W in LDS, VGPR=36, 16-deep gather) with LB 4 -> 8:
// same 1563 blocks (same per-block costs -- the R13 trap was 2x blocks),
// but all 6.1 waves/SIMD co-resident -> one round, deeper wait-overlap.
__global__ __launch_bounds__(TPB, 8)
void k_gather_gemm(const u16* __restrict__ h, const int* __restrict__ offs,
                   const int* __restrict__ csr,
                   const float* __restrict__ W, const float* __restrict__ bias,
                   float* __restrict__ Y, float* __restrict__ stats,
                   int N, int nodesPerWave) {
    __shared__ float Wl[F * F];
    int t = threadIdx.x;
    int lane = t & 63, w = t >> 6;
    for (int i = t; i < F * F; i += TPB) Wl[i] = W[i];
    __syncthreads();
    float bj = bias[lane];
    int node0 = (blockIdx.x * 4 + w) * nodesPerWave;
    // offs[node0 .. node0+NPW] via lanes (clamped), broadcast later by readlane
    int off_l = 0;
    if (lane <= nodesPerWave) off_l = offs[min(node0 + lane, N)];
    float s1 = 0.f, s2 = 0.f;
    // prefetch node 0's first batch
    int start_n = lane_bcast_i(off_l, 0);
    int end_n   = lane_bcast_i(off_l, 1);
    int cnt_n   = min(end_n - start_n, 64);
    int idx_n   = (lane < cnt_n) ? csr[start_n + lane] : 0;
    for (int r = 0; r < nodesPerWave; ++r) {
        int node = node0 + r;
        if (node >= N) break;
        int start = start_n, end = end_n, cnt = cnt_n, idx = idx_n;
        // prefetch next node's first batch (clamped offs make this safe)
        if (r + 1 < nodesPerWave) {
            start_n = lane_bcast_i(off_l, r + 1);
            end_n   = lane_bcast_i(off_l, r + 2);
            cnt_n   = min(end_n - start_n, 64);
            idx_n   = (lane < cnt_n) ? csr[start_n + lane] : 0;
        }
        float agg = bf2f(h[(size_t)node * F + lane]);    // GIN self term (eps=0)
        // first batch (prefetched idx)
        {
            int k = 0;
            for (; k + 16 <= cnt; k += 16) {
                float vv[16];
#pragma unroll
                for (int u = 0; u < 16; ++u)
                    vv[u] = bf2f(h[(size_t)lane_bcast_i(idx, k + u) * F + lane]);
                float sA = 0.f, sB = 0.f, sC = 0.f, sD = 0.f;
#pragma unroll
                for (int u = 0; u < 4; ++u) {
                    sA += vv[u]; sB += vv[4 + u]; sC += vv[8 + u]; sD += vv[12 + u];
                }
                agg += (sA + sB) + (sC + sD);
            }
            for (; k + 4 <= cnt; k += 4) {
                float v0 = bf2f(h[(size_t)lane_bcast_i(idx, k)     * F + lane]);
                float v1 = bf2f(h[(size_t)lane_bcast_i(idx, k + 1) * F + lane]);
                float v2 = bf2f(h[(size_t)lane_bcast_i(idx, k + 2) * F + lane]);
                float v3 = bf2f(h[(size_t)lane_bcast_i(idx, k + 3) * F + lane]);
                agg += (v0 + v1) + (v2 + v3);
            }
            for (; k < cnt; ++k)
                agg += bf2f(h[(size_t)lane_bcast_i(idx, k) * F + lane]);
        }
        // remaining batches (degree > 64, rare)
        for (int base = start + 64; base < end; base += 64) {
            int c2 = end - base; if (c2 > 64) c2 = 64;
            int idx2 = (lane < c2) ? csr[base + lane] : 0;
            int k = 0;
            for (; k + 4 <= c2; k += 4) {
                float v0 = bf2f(h[(size_t)lane_bcast_i(idx2, k)     * F + lane]);
                float v1 = bf2f(h[(size_t)lane_bcast_i(idx2, k + 1) * F + lane]);
                float v2 = bf2f(h[(size_t)lane_bcast_i(idx2, k + 2) * F + lane]);
                float v3 = bf2f(h[(size_t)lane_bcast_i(idx2, k + 3) * F + lane]);
                agg += (v0 + v1) + (v2 + v3);
            }
            for (; k < c2; ++k)
                agg += bf2f(h[(size_t)lane_bcast_i(idx2, k) * F + lane]);
        }
        // GEMM from LDS W (stride-64 f32 = 2-way bank aliasing = free)
        float acc = bj;
#pragma unroll
        for (int f = 0; f < F; ++f) acc += lane_bcast(agg, f) * Wl[f * F + lane];
        Y[(size_t)node * F + lane] = acc;
        s1 += acc;
        s2 += acc * acc;
    }
    __shared__ float red[TPB];
    red[t] = s1; __syncthreads();
    if (w == 0) atomicAdd(&stats[lane], red[lane] + red[64 + lane] + red[128 + lane] + red[192 + lane]);
    __syncthreads();
    red[t] = s2; __syncthreads();
    if (w == 0) atomicAdd(&stats[64 + lane], red[lane] + red[64 + lane] + red[128 + lane] + red[192 + lane]);
}

// ---- fused: BN(Y)+ReLU -> GEMM2 -> ReLU -> Hout(bf16); Yf += Hout @ Wj --
__global__ __launch_bounds__(TPB, 3)
void k_layerB(const float* __restrict__ Y, const float* __restrict__ stats,
              const float* __restrict__ g, const float* __restrict__ bt,
              const float* __restrict__ W2, const float* __restrict__ b2,
              const float* __restrict__ Wj,
              u16* __restrict__ Hout, float* __restrict__ Yf,
              float* __restrict__ stats5, int N, int rowsPerWave, int doHead) {
    int t = threadIdx.x;
    int lane = t & 63, w = t >> 6;
    float wc2[F], wcj[F];
#pragma unroll
    for (int f = 0; f < F; ++f) { wc2[f] = W2[f * F + lane]; wcj[f] = Wj[f * F + lane]; }
    float mu = stats[lane] / (float)N;
    float var = stats[64 + lane] / (float)N - mu * mu;
    float rs = rsqrtf(var + BN_EPS);
    float sc = rs * g[lane];
    float sh = bt[lane] - mu * sc;
    float bj = b2[lane];
    int row0 = (blockIdx.x * 4 + w) * rowsPerWave;
    float s1 = 0.f, s2 = 0.f;
    for (int r = 0; r < rowsPerWave; ++r) {
        int row = row0 + r;
        if (row >= N) break;
        float v = fmaxf(Y[(size_t)row * F + lane] * sc + sh, 0.f);
        float acc = bj;
#pragma unroll
        for (int f = 0; f < F; ++f) acc += lane_bcast(v, f) * wc2[f];
        float hv = fmaxf(acc, 0.f);
        Hout[(size_t)row * F + lane] = f2bf(hv);
        float yf = Yf[(size_t)row * F + lane];
#pragma unroll
        for (int f = 0; f < F; ++f) yf += lane_bcast(hv, f) * wcj[f];
        Yf[(size_t)row * F + lane] = yf;
        if (doHead) { s1 += yf; s2 += yf * yf; }
    }
    if (doHead) {
        __shared__ float red[TPB];
        red[t] = s1; __syncthreads();
        if (w == 0) atomicAdd(&stats5[lane], red[lane] + red[64 + lane] + red[128 + lane] + red[192 + lane]);
        __syncthreads();
        red[t] = s2; __syncthreads();
        if (w == 0) atomicAdd(&stats5[64 + lane], red[lane] + red[64 + lane] + red[128 + lane] + red[192 + lane]);
    }
}

// ---- head: BN(Yf)+ReLU -> @mlpW2+b2 -> pooled add into out[graph] -------
__global__ __launch_bounds__(TPB, 4)
void k_final(const float* __restrict__ Yf, const float* __restrict__ stats,
             const float* __restrict__ g, const float* __restrict__ bt,
             const float* __restrict__ W2, const float* __restrict__ b2,
             const int* __restrict__ batch, float* __restrict__ out,
             int N, int rowsPerWave) {
    int t = threadIdx.x;
    int lane = t & 63, w = t >> 6;
    float wcol[F];
#pragma unroll
    for (int f = 0; f < F; ++f) wcol[f] = W2[f * F + lane];
    float mu = stats[lane] / (float)N;
    float var = stats[64 + lane] / (float)N - mu * mu;
    float rs = rsqrtf(var + BN_EPS);
    float sc = rs * g[lane];
    float sh = bt[lane] - mu * sc;
    float bj = b2[lane];
    int row0 = (blockIdx.x * 4 + w) * rowsPerWave;
    int curg = -1;
    float accg = 0.f;
    for (int r = 0; r < rowsPerWave; ++r) {
        int row = row0 + r;
        if (row >= N) break;
        float v = fmaxf(Yf[(size_t)row * F + lane] * sc + sh, 0.f);
        float acc = bj;
#pragma unroll
        for (int f = 0; f < F; ++f) acc += lane_bcast(v, f) * wcol[f];
        int gid = batch[row];
        if (gid != curg) {
            if (curg >= 0) atomicAdd(&out[(size_t)curg * F + lane], accg);
            curg = gid;
            accg = 0.f;
        }
        accg += acc;
    }
    if (curg >= 0) atomicAdd(&out[(size_t)curg * F + lane], accg);
}

// ---- launcher -----------------------------------------------------------

extern "C" void kernel_launch(void* const* d_in, const int* in_sizes, int n_in,
                              void* d_out, int out_size, void* d_ws, size_t ws_size,
                              hipStream_t stream) {
    const float* x      = (const float*)d_in[0];
    const int*   ei     = (const int*)d_in[1];
    const int*   batch  = (const int*)d_in[2];
    const float* convW1 = (const float*)d_in[3];
    const float* convb1 = (const float*)d_in[4];
    const float* convg  = (const float*)d_in[5];
    const float* convbt = (const float*)d_in[6];
    const float* convW2 = (const float*)d_in[7];
    const float* convb2 = (const float*)d_in[8];
    const float* mlpW1  = (const float*)d_in[9];
    const float* mlpb1  = (const float*)d_in[10];
    const float* mlpg   = (const float*)d_in[11];
    const float* mlpbt  = (const float*)d_in[12];
    const float* mlpW2  = (const float*)d_in[13];
    const float* mlpb2  = (const float*)d_in[14];

    const int N = in_sizes[0] / F;             // 50000
    const int E = in_sizes[1] / 2;             // 800000
    const int L = in_sizes[3] / (F * F);       // 5

    const int* src = ei;
    const int* dst = ei + E;

    char* w = (char*)d_ws;
    size_t off = 0;
    auto alloc = [&](size_t bytes) {
        void* p = w + off;
        off = (off + bytes + 255) & ~(size_t)255;
        return p;
    };
    u16*   x16     = (u16*)alloc((size_t)N * F * 2);
    u16*   hA16    = (u16*)alloc((size_t)N * F * 2);
    u16*   hB16    = (u16*)alloc((size_t)N * F * 2);
    float* Ytmp    = (float*)alloc((size_t)N * F * 4);
    float* Yf      = (float*)alloc((size_t)N * F * 4);
    int*   deg     = (int*)alloc((size_t)N * 4);
    int*   offs    = (int*)alloc((size_t)(N + 1) * 4);
    int*   cursor  = (int*)alloc((size_t)N * 4);
    int*   csr_src = (int*)alloc((size_t)E * 4);
    int*   part    = (int*)alloc((size_t)SCAN_B * 4);
    float* stats   = (float*)alloc((size_t)(L + 1) * 128 * 4);

    hipMemsetAsync(deg, 0, (size_t)N * 4, stream);
    hipMemsetAsync(stats, 0, (size_t)(L + 1) * 128 * 4, stream);
    hipMemsetAsync(d_out, 0, (size_t)out_size * 4, stream);

    const int edgeBlocks = (E + TPB - 1) / TPB;

    k_hist<<<edgeBlocks, TPB, 0, stream>>>(dst, deg, E);
    k_scan_part<<<SCAN_B, TPB, 0, stream>>>(deg, part, N);
    k_scan_apply<<<SCAN_B, TPB, 0, stream>>>(deg, part, offs, cursor, N);
    k_fill<<<edgeBlocks, TPB, 0, stream>>>(src, dst, cursor, csr_src, E);

    const int NPW_A = 8;     // R12 proven config; 1563 blocks
    const int RPW   = 8;
    const int RPW_F = 16;
    const int blocksA = (N + 4 * NPW_A - 1) / (4 * NPW_A);
    const int blocksD = (N + 4 * RPW - 1) / (4 * RPW);
    const int blocksF = (N + 4 * RPW_F - 1) / (4 * RPW_F);

    // fused bf16-convert + JK-init (reads x once)
    k_prep<<<blocksD, TPB, 0, stream>>>(x, x16, mlpW1, mlpb1, Yf, N, RPW);

    const u16* h_cur = x16;
    for (int l = 0; l < L; ++l) {
        u16* h_next = (l & 1) ? hB16 : hA16;
        k_gather_gemm<<<blocksA, TPB, 0, stream>>>(h_cur, offs, csr_src,
                                                   convW1 + l * F * F, convb1 + l * F,
                                                   Ytmp, stats + l * 128, N, NPW_A);
        k_layerB<<<blocksD, TPB, 0, stream>>>(Ytmp, stats + l * 128,
                                              convg + l * F, convbt + l * F,
                                              convW2 + l * F * F, convb2 + l * F,
                                              mlpW1 + (l + 1) * F * F,
                                              h_next, Yf, stats + L * 128,
                                              N, RPW, l == L - 1);
        h_cur = h_next;
    }

    k_final<<<blocksF, TPB, 0, stream>>>(Yf, stats + L * 128, mlpg, mlpbt,
                                         mlpW2, mlpb2, batch, (float*)d_out, N, RPW_F);
}